// Round 11
// baseline (198.807 us; speedup 1.0000x reference)
//
#include <hip/hip_runtime.h>

typedef unsigned short ushort_t;
typedef unsigned int uint_t;
typedef __attribute__((ext_vector_type(8))) short short8;
typedef __attribute__((ext_vector_type(4))) float floatx4;

#define S_LEN 2048
#define D_DIM 1024
#define H_NUM 16
#define HD 64
#define GBUF (128 * 32)
#define A64 (128 * 32)
#define B64 (64 * 32)

__device__ __forceinline__ float bf2f(ushort_t u) {
    union { uint_t i; float f; } c; c.i = ((uint_t)u) << 16; return c.f;
}
__device__ __forceinline__ ushort_t f2bf(float f) {
    union { float f; uint_t i; } c; c.f = f;
    uint_t r = c.i + 0x7fffu + ((c.i >> 16) & 1u);
    return (ushort_t)(r >> 16);
}

// async global->LDS, 16B per lane. LDS dest must be wave-uniform base + lane*16.
__device__ __forceinline__ void g2l16(const ushort_t* g, ushort_t* l) {
    __builtin_amdgcn_global_load_lds(
        (const __attribute__((address_space(1))) void*)g,
        (__attribute__((address_space(3))) void*)l, 16, 0, 0);
}

// ---------------------------------------------------------------- cast x
__global__ __launch_bounds__(256, 4) void cast_x_kernel(
        const float* __restrict__ in, ushort_t* __restrict__ out) {
    const int idx = (blockIdx.x * 256 + threadIdx.x) * 4;
    const float4 v = *(const float4*)(in + idx);
    ushort4 o;
    o.x = f2bf(v.x); o.y = f2bf(v.y); o.z = f2bf(v.z); o.w = f2bf(v.w);
    *(ushort4*)(out + idx) = o;
}

// ---------------------------------------------------------------- transpose+cast (validated R3)
__global__ __launch_bounds__(256, 2) void transpose4_kernel(
        const float* __restrict__ W0, const float* __restrict__ W1,
        const float* __restrict__ W2, const float* __restrict__ W3,
        ushort_t* __restrict__ T0, ushort_t* __restrict__ T1,
        ushort_t* __restrict__ T2, ushort_t* __restrict__ T3) {
    const int z = blockIdx.z;
    const float* in  = (z == 0) ? W0 : (z == 1) ? W1 : (z == 2) ? W2 : W3;
    ushort_t*    out = (z == 0) ? T0 : (z == 1) ? T1 : (z == 2) ? T2 : T3;
    __shared__ __align__(16) ushort_t t[64][65];
    const int r0 = blockIdx.y * 64, c0 = blockIdx.x * 64;
    const int tr = threadIdx.x >> 4;
    const int tc = (threadIdx.x & 15) * 4;
#pragma unroll
    for (int i = 0; i < 4; ++i) {
        const int row = tr + i * 16;
        const float4 v = *(const float4*)(in + (size_t)(r0 + row) * D_DIM + c0 + tc);
        t[row][tc + 0] = f2bf(v.x); t[row][tc + 1] = f2bf(v.y);
        t[row][tc + 2] = f2bf(v.z); t[row][tc + 3] = f2bf(v.w);
    }
    __syncthreads();
#pragma unroll
    for (int i = 0; i < 4; ++i) {
        const int n = tr + i * 16;
        ushort4 v;
        v.x = t[tc + 0][n]; v.y = t[tc + 1][n];
        v.z = t[tc + 2][n]; v.w = t[tc + 3][n];
        *(ushort4*)(out + (size_t)(c0 + n) * D_DIM + r0 + tc) = v;
    }
}

// ---------------------------------------------------------------- MFMA GEMM tile (128x128)
// T4 counted-vmcnt 3-buffer pipeline (R10-validated correct). Raw s_barrier
// + "s_waitcnt vmcnt(4) lgkmcnt(0)" at loop head; tiles k+1,k+2 in flight
// across barriers; last iter vmcnt(0).
__device__ __forceinline__ void gemm_tile(
        const ushort_t* __restrict__ A, const ushort_t* __restrict__ BT,
        const int m0, const int n0,
        ushort_t* As, ushort_t* Bs, floatx4 acc[4][4]) {
    const int tid  = threadIdx.x;
    const int w    = tid >> 6;
    const int wm   = (w >> 1) * 64;
    const int wn   = (w & 1) * 64;
    const int lrow = tid & 15;
    const int kq   = ((tid & 63) >> 4) * 8;

    const int flat0 = tid * 8;
    const int flat1 = (256 + tid) * 8;
    const int row0 = flat0 >> 5, kk0 = flat0 & 31;
    const int row1 = flat1 >> 5, kk1 = flat1 & 31;

    const ushort_t* ga0 = A  + (size_t)(m0 + row0) * D_DIM + kk0;
    const ushort_t* gb0 = BT + (size_t)(n0 + row0) * D_DIM + kk0;
    const ushort_t* ga1 = A  + (size_t)(m0 + row1) * D_DIM + kk1;
    const ushort_t* gb1 = BT + (size_t)(n0 + row1) * D_DIM + kk1;

    const int nsteps = D_DIM / 32;           // 32

    // prologue: stage tiles 0 and 1 into buffers 0 and 1 (8 loads in flight)
    g2l16(ga0, As + flat0);
    g2l16(gb0, Bs + flat0);
    g2l16(ga1, As + flat1);
    g2l16(gb1, Bs + flat1);
    g2l16(ga0 + 32, As + GBUF + flat0);
    g2l16(gb0 + 32, Bs + GBUF + flat0);
    g2l16(ga1 + 32, As + GBUF + flat1);
    g2l16(gb1 + 32, Bs + GBUF + flat1);

    int cur = 0;                             // buffer index k%3
    for (int k = 0; k < nsteps; ++k) {
        if (k == nsteps - 1)
            asm volatile("s_waitcnt vmcnt(0) lgkmcnt(0)" ::: "memory");
        else
            asm volatile("s_waitcnt vmcnt(4) lgkmcnt(0)" ::: "memory");
        __builtin_amdgcn_sched_barrier(0);
        __builtin_amdgcn_s_barrier();

        const ushort_t* Ac = As + cur * GBUF;
        const ushort_t* Bc = Bs + cur * GBUF;
        short8 av[4], bv[4];
#pragma unroll
        for (int i = 0; i < 4; ++i)
            av[i] = *(const short8*)(Ac + (wm + i * 16 + lrow) * 32 + kq);
#pragma unroll
        for (int j = 0; j < 4; ++j)
            bv[j] = *(const short8*)(Bc + (wn + j * 16 + lrow) * 32 + kq);

        if (k + 2 < nsteps) {                // issue tile k+2 into buffer (k+2)%3
            const int nb = (cur + 2 >= 3) ? cur - 1 : cur + 2;
            ushort_t* An = As + nb * GBUF;
            ushort_t* Bn = Bs + nb * GBUF;
            const int ko = (k + 2) * 32;
            g2l16(ga0 + ko, An + flat0);
            g2l16(gb0 + ko, Bn + flat0);
            g2l16(ga1 + ko, An + flat1);
            g2l16(gb1 + ko, Bn + flat1);
        }

#pragma unroll
        for (int i = 0; i < 4; ++i)
#pragma unroll
            for (int j = 0; j < 4; ++j)
                acc[i][j] = __builtin_amdgcn_mfma_f32_16x16x32_bf16(
                    av[i], bv[j], acc[i][j], 0, 0, 0);

        cur = (cur + 1 >= 3) ? 0 : cur + 1;
    }
}

// ---------------------------------------------------------------- MFMA GEMM tile (128x64)
// R11: for gemm_out only. Grid doubles to 512 blocks -> 2 blocks/CU =
// 2 waves/SIMD (was 1 -- fully latency-exposed). Same counted-vmcnt
// 3-buffer pipeline; 3 loads/thread/tile -> steady vmcnt(3).
__device__ __forceinline__ void gemm_tile_n64(
        const ushort_t* __restrict__ A, const ushort_t* __restrict__ BT,
        const int m0, const int n0,
        ushort_t* As, ushort_t* Bs, floatx4 acc[4][2]) {
    const int tid  = threadIdx.x;
    const int w    = tid >> 6;
    const int wm   = (w >> 1) * 64;
    const int wn   = (w & 1) * 32;
    const int lrow = tid & 15;
    const int kq   = ((tid & 63) >> 4) * 8;

    const int flat0 = tid * 8;                 // A elems 0..2047
    const int flat1 = (256 + tid) * 8;         // A elems 2048..4095
    const int rowA0 = flat0 >> 5, kkA0 = flat0 & 31;
    const int rowA1 = flat1 >> 5, kkA1 = flat1 & 31;
    const int rowB  = tid >> 2,  kkB  = (tid & 3) * 8;   // B rows 0..63

    const ushort_t* ga0 = A  + (size_t)(m0 + rowA0) * D_DIM + kkA0;
    const ushort_t* ga1 = A  + (size_t)(m0 + rowA1) * D_DIM + kkA1;
    const ushort_t* gb  = BT + (size_t)(n0 + rowB)  * D_DIM + kkB;

    const int nsteps = D_DIM / 32;

    // prologue: tiles 0,1 (6 loads in flight)
    g2l16(ga0, As + flat0);
    g2l16(ga1, As + flat1);
    g2l16(gb,  Bs + tid * 8);
    g2l16(ga0 + 32, As + A64 + flat0);
    g2l16(ga1 + 32, As + A64 + flat1);
    g2l16(gb  + 32, Bs + B64 + tid * 8);

    int cur = 0;
    for (int k = 0; k < nsteps; ++k) {
        if (k == nsteps - 1)
            asm volatile("s_waitcnt vmcnt(0) lgkmcnt(0)" ::: "memory");
        else
            asm volatile("s_waitcnt vmcnt(3) lgkmcnt(0)" ::: "memory");
        __builtin_amdgcn_sched_barrier(0);
        __builtin_amdgcn_s_barrier();

        const ushort_t* Ac = As + cur * A64;
        const ushort_t* Bc = Bs + cur * B64;
        short8 av[4], bv[2];
#pragma unroll
        for (int i = 0; i < 4; ++i)
            av[i] = *(const short8*)(Ac + (wm + i * 16 + lrow) * 32 + kq);
#pragma unroll
        for (int j = 0; j < 2; ++j)
            bv[j] = *(const short8*)(Bc + (wn + j * 16 + lrow) * 32 + kq);

        if (k + 2 < nsteps) {
            const int nb = (cur + 2 >= 3) ? cur - 1 : cur + 2;
            const int ko = (k + 2) * 32;
            g2l16(ga0 + ko, As + nb * A64 + flat0);
            g2l16(ga1 + ko, As + nb * A64 + flat1);
            g2l16(gb  + ko, Bs + nb * B64 + tid * 8);
        }

#pragma unroll
        for (int i = 0; i < 4; ++i)
#pragma unroll
            for (int j = 0; j < 2; ++j)
                acc[i][j] = __builtin_amdgcn_mfma_f32_16x16x32_bf16(
                    av[i], bv[j], acc[i][j], 0, 0, 0);

        cur = (cur + 1 >= 3) ? 0 : cur + 1;
    }
}

// QKV: z picks weight/dest; writes merged row-major [B*S, D] bf16.
// Q pre-scaled by 0.125*log2(e): attention softmax runs in exp2 domain.
// LDS 3x16KB = 48KB -> 3 blocks/CU = 144KB (fits 160KB).
__global__ __launch_bounds__(256, 3) void gemm_qkv_kernel(
        const ushort_t* __restrict__ A,
        const ushort_t* __restrict__ WqT, const ushort_t* __restrict__ WkT,
        const ushort_t* __restrict__ WvT,
        ushort_t* __restrict__ Qo, ushort_t* __restrict__ Ko,
        ushort_t* __restrict__ Vo) {
    const ushort_t* BT = (blockIdx.z == 0) ? WqT : (blockIdx.z == 1) ? WkT : WvT;
    ushort_t* C        = (blockIdx.z == 0) ? Qo  : (blockIdx.z == 1) ? Ko  : Vo;
    const float sc     = (blockIdx.z == 0) ? 0.18033688f : 1.0f;  // 0.125*log2(e)
    __shared__ __align__(16) ushort_t As[3 * GBUF];
    __shared__ __align__(16) ushort_t Bs[3 * GBUF];
    const int m0 = blockIdx.y * 128, n0 = blockIdx.x * 128;

    floatx4 acc[4][4] = {};
    gemm_tile(A, BT, m0, n0, As, Bs, acc);

    const int tid = threadIdx.x;
    const int w = tid >> 6, wm = (w >> 1) * 64, wn = (w & 1) * 64;
    const int lrow = tid & 15;
    const int rquad = ((tid & 63) >> 4) * 4;
#pragma unroll
    for (int i = 0; i < 4; ++i) {
        const int mbase = m0 + wm + i * 16 + rquad;
#pragma unroll
        for (int j = 0; j < 4; ++j) {
            const int gn = n0 + wn + j * 16 + lrow;
#pragma unroll
            for (int r = 0; r < 4; ++r)
                C[(size_t)(mbase + r) * D_DIM + gn] = f2bf(acc[i][j][r] * sc);
        }
    }
}

// Output projection: f32 out = A @ Wo + bo. R11: 128x64 tile -> grid 512
// blocks = 2 blocks/CU (was 256 = 1/CU = 1 wave/SIMD, fully latency-bound
// at ~160 TF while qkv ran ~430 TF on the same structure). LDS 36KB.
__global__ __launch_bounds__(256, 3) void gemm_out_kernel(
        const ushort_t* __restrict__ A, const ushort_t* __restrict__ WoT,
        const float* __restrict__ bias, float* __restrict__ C) {
    __shared__ __align__(16) ushort_t As[3 * A64];
    __shared__ __align__(16) ushort_t Bs[3 * B64];
    const int m0 = blockIdx.y * 128, n0 = blockIdx.x * 64;

    floatx4 acc[4][2] = {};
    gemm_tile_n64(A, WoT, m0, n0, As, Bs, acc);

    const int tid = threadIdx.x;
    const int w = tid >> 6, wm = (w >> 1) * 64, wn = (w & 1) * 32;
    const int lrow = tid & 15;
    const int rquad = ((tid & 63) >> 4) * 4;
#pragma unroll
    for (int i = 0; i < 4; ++i) {
        const int mbase = m0 + wm + i * 16 + rquad;
#pragma unroll
        for (int j = 0; j < 2; ++j) {
            const int gn = n0 + wn + j * 16 + lrow;
            const float badd = bias[gn];
#pragma unroll
            for (int r = 0; r < 4; ++r)
                C[(size_t)(mbase + r) * D_DIM + gn] = acc[i][j][r] + badd;
        }
    }
}

// ---------------------------------------------------------------- MFMA flash attention
// Byte-identical to R10/R8 (67us known-good). 256 thr / 4 waves, q-tile 64,
// static (bh,y) grid: XCD = bh%8 L2 affinity; CU-balanced qt map.
// Conflict-free swizzled LDS; exp2-domain softmax (log2(e) folded into Q);
// T14 register prefetch of next K/V tile; l-sum deferred to epilogue.
__global__ __launch_bounds__(256, 4) void attn_mfma_kernel(
        const ushort_t* __restrict__ Q, const ushort_t* __restrict__ K,
        const ushort_t* __restrict__ V, ushort_t* __restrict__ O) {
    __shared__ __align__(16) ushort_t Ks[64 * 64];      // [key][d] swizzled
    __shared__ __align__(16) ushort_t Vt[64 * 64];      // [d][key] swizzled
    __shared__ __align__(16) ushort_t Ps[4][16 * 64];   // per-wave P [row][key] swizzled

    const int bh  = blockIdx.x;
    const int b   = bh >> 4, h = bh & 15;
    const int g   = blockIdx.y & 7;            // CU-balanced qt map
    const int p   = blockIdx.y >> 3;
    const int qt  = (p == 0) ? g : (p == 1) ? (15 - g)
                  : (p == 2) ? (16 + g) : (31 - g);
    const int q0  = qt * 64;
    const int tid = threadIdx.x;
    const int wq  = tid >> 6;
    const int lane = tid & 63;
    const int col  = lane & 15;
    const int quad = lane >> 4;
    const int c7 = col & 7;
    const int qw0  = q0 + wq * 16;             // wave's first q-row
    const size_t rowbase = (size_t)b * S_LEN;
    const int ch0 = h * HD;

    // K staging: thread = (key, 32B d-chunk)
    const int skey = tid >> 2;           // 0..63
    const int schk = tid & 3;            // 0..3
    // V staging: thread = (key-pair, 8-wide d-chunk)
    const int vkp = tid & 31;            // key-pair 0..31
    const int vdc = tid >> 5;            // d-chunk 0..7

    // Q A-fragments: lane holds A[m=col][k=quad*8+e]
    short8 aq[2];
#pragma unroll
    for (int kc = 0; kc < 2; ++kc)
        aq[kc] = *(const short8*)(Q + (rowbase + qw0 + col) * D_DIM
                                    + ch0 + kc * 32 + quad * 8);

    floatx4 oacc[4] = {};
    float mrun[4], lrun[4];
#pragma unroll
    for (int r = 0; r < 4; ++r) { mrun[r] = -1e30f; lrun[r] = 0.0f; }

    const int ntiles = qt + 1;

    // ---- prologue: load tile 0 into registers
    short8 krA, krB, vrA, vrB;
    {
        const ushort_t* kg = K + (rowbase + skey) * D_DIM + ch0 + schk * 16;
        krA = *(const short8*)(kg);
        krB = *(const short8*)(kg + 8);
        const ushort_t* vg = V + (rowbase + 2 * vkp) * D_DIM + ch0 + vdc * 8;
        vrA = *(const short8*)(vg);
        vrB = *(const short8*)(vg + D_DIM);
    }

    for (int t = 0; t < ntiles; ++t) {
        const int kb = t * 64;
        __syncthreads();   // previous tile's LDS reads complete
        // ---- write staged registers to LDS (K swizzled, V transposed pair-packed)
        {
            const int sw = skey & 7;
            *(short8*)(Ks + skey * 64 + (((2 * schk) ^ sw) << 3)) = krA;
            *(short8*)(Ks + skey * 64 + (((2 * schk + 1) ^ sw) << 3)) = krB;
        }
#pragma unroll
        for (int e = 0; e < 8; ++e) {
            const int d = vdc * 8 + e;
            const uint_t pk = (uint_t)(ushort_t)vrA[e] | ((uint_t)(ushort_t)vrB[e] << 16);
            *(uint_t*)(Vt + d * 64 + ((2 * vkp) ^ ((d & 7) << 3))) = pk;
        }
        // ---- prefetch next tile into registers (overlaps with compute below)
        {
            const int kbn = (t + 1 < ntiles) ? (t + 1) * 64 : 0;   // clamp: valid addr
            const ushort_t* kg = K + (rowbase + kbn + skey) * D_DIM + ch0 + schk * 16;
            krA = *(const short8*)(kg);
            krB = *(const short8*)(kg + 8);
            const ushort_t* vg = V + (rowbase + kbn + 2 * vkp) * D_DIM + ch0 + vdc * 8;
            vrA = *(const short8*)(vg);
            vrB = *(const short8*)(vg + D_DIM);
        }
        __syncthreads();   // LDS tile ready

        if (kb <= qw0 + 15) {        // wave-uniform: tile has valid keys
            // ---- S = Q K^T (one ds_read_b128 per fragment, conflict-free)
            floatx4 sa[4] = {};
            __builtin_amdgcn_s_setprio(1);
#pragma unroll
            for (int kc = 0; kc < 2; ++kc)
#pragma unroll
                for (int j = 0; j < 4; ++j) {
                    const short8 bk = *(const short8*)(
                        Ks + (j * 16 + col) * 64 + (((kc * 4 + quad) ^ c7) << 3));
                    sa[j] = __builtin_amdgcn_mfma_f32_16x16x32_bf16(
                        aq[kc], bk, sa[j], 0, 0, 0);
                }
            __builtin_amdgcn_s_setprio(0);

            const bool needmask = (kb + 63 > qw0);
            // ---- causal mask (scale pre-folded into Q)
            if (needmask) {
#pragma unroll
                for (int j = 0; j < 4; ++j)
#pragma unroll
                    for (int r = 0; r < 4; ++r) {
                        const int row = qw0 + quad * 4 + r;
                        const int key = kb + j * 16 + col;
                        if (key > row) sa[j][r] = -1e30f;
                    }
            }
            // ---- online softmax per row, exp2 domain (straight-line)
#pragma unroll
            for (int r = 0; r < 4; ++r) {
                float mx = fmaxf(fmaxf(sa[0][r], sa[1][r]),
                                 fmaxf(sa[2][r], sa[3][r]));
                mx = fmaxf(mx, __shfl_xor(mx, 1));
                mx = fmaxf(mx, __shfl_xor(mx, 2));
                mx = fmaxf(mx, __shfl_xor(mx, 4));
                mx = fmaxf(mx, __shfl_xor(mx, 8));
                const float mn = fmaxf(mrun[r], mx);
                const float al = __builtin_amdgcn_exp2f(mrun[r] - mn);
                mrun[r] = mn;
                float rs = 0.0f;
#pragma unroll
                for (int j = 0; j < 4; ++j) {
                    const float p2 = __builtin_amdgcn_exp2f(sa[j][r] - mn);
                    sa[j][r] = p2;
                    rs += p2;
                }
                lrun[r] = lrun[r] * al + rs;
#pragma unroll
                for (int jd = 0; jd < 4; ++jd) oacc[jd][r] *= al;
            }
            // ---- write P (bf16) to this wave's swizzled LDS region
            {
                ushort_t* pw = Ps[wq];
#pragma unroll
                for (int j = 0; j < 4; ++j)
#pragma unroll
                    for (int r = 0; r < 4; ++r) {
                        const int row = quad * 4 + r;
                        pw[row * 64 + ((j * 16 + col) ^ ((row & 7) << 3))] =
                            f2bf(sa[j][r]);
                    }
            }
            asm volatile("s_waitcnt lgkmcnt(0)" ::: "memory");   // wave-local RAW
            // ---- O += P V
            __builtin_amdgcn_s_setprio(1);
#pragma unroll
            for (int kc = 0; kc < 2; ++kc) {
                const short8 ap = *(const short8*)(
                    Ps[wq] + col * 64 + (((kc * 4 + quad) ^ c7) << 3));
#pragma unroll
                for (int jd = 0; jd < 4; ++jd) {
                    const short8 bv = *(const short8*)(
                        Vt + (jd * 16 + col) * 64 + (((kc * 4 + quad) ^ c7) << 3));
                    oacc[jd] = __builtin_amdgcn_mfma_f32_16x16x32_bf16(
                        ap, bv, oacc[jd], 0, 0, 0);
                }
            }
            __builtin_amdgcn_s_setprio(0);
        }
    }

    // ---- epilogue: reduce l across the 16 key-lanes, write O bf16
#pragma unroll
    for (int r = 0; r < 4; ++r) {
        float l = lrun[r];
        l += __shfl_xor(l, 1);
        l += __shfl_xor(l, 2);
        l += __shfl_xor(l, 4);
        l += __shfl_xor(l, 8);
        const int row = qw0 + quad * 4 + r;
        const float inv = 1.0f / l;
#pragma unroll
        for (int jd = 0; jd < 4; ++jd)
            O[(rowbase + row) * D_DIM + ch0 + jd * 16 + col] =
                f2bf(oacc[jd][r] * inv);
    }
}

// ---------------------------------------------------------------- launch
extern "C" void kernel_launch(void* const* d_in, const int* in_sizes, int n_in,
                              void* d_out, int out_size, void* d_ws, size_t ws_size,
                              hipStream_t stream) {
    const float* x  = (const float*)d_in[0];
    const float* Wq = (const float*)d_in[1];
    const float* Wk = (const float*)d_in[2];
    const float* Wv = (const float*)d_in[3];
    const float* Wo = (const float*)d_in[4];
    const float* bo = (const float*)d_in[5];
    float* out = (float*)d_out;                // f32 output

    char* ws = (char*)d_ws;
    const size_t MB = 1024 * 1024;
    ushort_t* xb  = (ushort_t*)(ws + 0 * MB);   // 8 MB
    ushort_t* WqT = (ushort_t*)(ws + 8 * MB);   // 2 MB each
    ushort_t* WkT = (ushort_t*)(ws + 10 * MB);
    ushort_t* WvT = (ushort_t*)(ws + 12 * MB);
    ushort_t* WoT = (ushort_t*)(ws + 14 * MB);
    ushort_t* Qb  = (ushort_t*)(ws + 16 * MB);  // [B*S, D] bf16, 8 MB each
    ushort_t* Kb  = (ushort_t*)(ws + 24 * MB);
    ushort_t* Vb  = (ushort_t*)(ws + 32 * MB);
    ushort_t* Ob  = (ushort_t*)(ws + 40 * MB);  // total 48 MB

    cast_x_kernel<<<4096, 256, 0, stream>>>(x, xb);
    transpose4_kernel<<<dim3(16, 16, 4), 256, 0, stream>>>(
        Wq, Wk, Wv, Wo, WqT, WkT, WvT, WoT);

    gemm_qkv_kernel<<<dim3(8, 32, 3), 256, 0, stream>>>(
        xb, WqT, WkT, WvT, Qb, Kb, Vb);

    attn_mfma_kernel<<<dim3(32, 32), 256, 0, stream>>>(Qb, Kb, Vb, Ob);

    gemm_out_kernel<<<dim3(16, 32), 256, 0, stream>>>(Ob, WoT, bo, out);
}

// Round 12
// 187.516 us; speedup vs baseline: 1.0602x; 1.0602x over previous
//
#include <hip/hip_runtime.h>

typedef unsigned short ushort_t;
typedef unsigned int uint_t;
typedef __attribute__((ext_vector_type(8))) short short8;
typedef __attribute__((ext_vector_type(4))) float floatx4;

#define S_LEN 2048
#define D_DIM 1024
#define H_NUM 16
#define HD 64
#define GBUF (128 * 32)

__device__ __forceinline__ float bf2f(ushort_t u) {
    union { uint_t i; float f; } c; c.i = ((uint_t)u) << 16; return c.f;
}
__device__ __forceinline__ ushort_t f2bf(float f) {
    union { float f; uint_t i; } c; c.f = f;
    uint_t r = c.i + 0x7fffu + ((c.i >> 16) & 1u);
    return (ushort_t)(r >> 16);
}
// packed f32x2 -> bf16x2 (RTNE, same rounding as f2bf)
__device__ __forceinline__ uint_t cvtpk_bf16(float lo, float hi) {
    uint_t d;
    asm("v_cvt_pk_bf16_f32 %0, %1, %2" : "=v"(d) : "v"(lo), "v"(hi));
    return d;
}

// async global->LDS, 16B per lane. LDS dest must be wave-uniform base + lane*16.
__device__ __forceinline__ void g2l16(const ushort_t* g, ushort_t* l) {
    __builtin_amdgcn_global_load_lds(
        (const __attribute__((address_space(1))) void*)g,
        (__attribute__((address_space(3))) void*)l, 16, 0, 0);
}

// ---------------------------------------------------------------- cast x
__global__ __launch_bounds__(256, 4) void cast_x_kernel(
        const float* __restrict__ in, ushort_t* __restrict__ out) {
    const int idx = (blockIdx.x * 256 + threadIdx.x) * 4;
    const float4 v = *(const float4*)(in + idx);
    ushort4 o;
    o.x = f2bf(v.x); o.y = f2bf(v.y); o.z = f2bf(v.z); o.w = f2bf(v.w);
    *(ushort4*)(out + idx) = o;
}

// ---------------------------------------------------------------- transpose+cast (validated R3)
__global__ __launch_bounds__(256, 2) void transpose4_kernel(
        const float* __restrict__ W0, const float* __restrict__ W1,
        const float* __restrict__ W2, const float* __restrict__ W3,
        ushort_t* __restrict__ T0, ushort_t* __restrict__ T1,
        ushort_t* __restrict__ T2, ushort_t* __restrict__ T3) {
    const int z = blockIdx.z;
    const float* in  = (z == 0) ? W0 : (z == 1) ? W1 : (z == 2) ? W2 : W3;
    ushort_t*    out = (z == 0) ? T0 : (z == 1) ? T1 : (z == 2) ? T2 : T3;
    __shared__ __align__(16) ushort_t t[64][65];
    const int r0 = blockIdx.y * 64, c0 = blockIdx.x * 64;
    const int tr = threadIdx.x >> 4;
    const int tc = (threadIdx.x & 15) * 4;
#pragma unroll
    for (int i = 0; i < 4; ++i) {
        const int row = tr + i * 16;
        const float4 v = *(const float4*)(in + (size_t)(r0 + row) * D_DIM + c0 + tc);
        t[row][tc + 0] = f2bf(v.x); t[row][tc + 1] = f2bf(v.y);
        t[row][tc + 2] = f2bf(v.z); t[row][tc + 3] = f2bf(v.w);
    }
    __syncthreads();
#pragma unroll
    for (int i = 0; i < 4; ++i) {
        const int n = tr + i * 16;
        ushort4 v;
        v.x = t[tc + 0][n]; v.y = t[tc + 1][n];
        v.z = t[tc + 2][n]; v.w = t[tc + 3][n];
        *(ushort4*)(out + (size_t)(c0 + n) * D_DIM + r0 + tc) = v;
    }
}

// ---------------------------------------------------------------- MFMA GEMM tile (128x128)
// T4 counted-vmcnt 3-buffer pipeline (R10-validated). Raw s_barrier +
// "s_waitcnt vmcnt(4) lgkmcnt(0)" at loop head; tiles k+1,k+2 in flight
// across barriers; last iter vmcnt(0).
__device__ __forceinline__ void gemm_tile(
        const ushort_t* __restrict__ A, const ushort_t* __restrict__ BT,
        const int m0, const int n0,
        ushort_t* As, ushort_t* Bs, floatx4 acc[4][4]) {
    const int tid  = threadIdx.x;
    const int w    = tid >> 6;
    const int wm   = (w >> 1) * 64;
    const int wn   = (w & 1) * 64;
    const int lrow = tid & 15;
    const int kq   = ((tid & 63) >> 4) * 8;

    const int flat0 = tid * 8;
    const int flat1 = (256 + tid) * 8;
    const int row0 = flat0 >> 5, kk0 = flat0 & 31;
    const int row1 = flat1 >> 5, kk1 = flat1 & 31;

    const ushort_t* ga0 = A  + (size_t)(m0 + row0) * D_DIM + kk0;
    const ushort_t* gb0 = BT + (size_t)(n0 + row0) * D_DIM + kk0;
    const ushort_t* ga1 = A  + (size_t)(m0 + row1) * D_DIM + kk1;
    const ushort_t* gb1 = BT + (size_t)(n0 + row1) * D_DIM + kk1;

    const int nsteps = D_DIM / 32;           // 32

    // prologue: stage tiles 0 and 1 into buffers 0 and 1 (8 loads in flight)
    g2l16(ga0, As + flat0);
    g2l16(gb0, Bs + flat0);
    g2l16(ga1, As + flat1);
    g2l16(gb1, Bs + flat1);
    g2l16(ga0 + 32, As + GBUF + flat0);
    g2l16(gb0 + 32, Bs + GBUF + flat0);
    g2l16(ga1 + 32, As + GBUF + flat1);
    g2l16(gb1 + 32, Bs + GBUF + flat1);

    int cur = 0;                             // buffer index k%3
    for (int k = 0; k < nsteps; ++k) {
        if (k == nsteps - 1)
            asm volatile("s_waitcnt vmcnt(0) lgkmcnt(0)" ::: "memory");
        else
            asm volatile("s_waitcnt vmcnt(4) lgkmcnt(0)" ::: "memory");
        __builtin_amdgcn_sched_barrier(0);
        __builtin_amdgcn_s_barrier();

        const ushort_t* Ac = As + cur * GBUF;
        const ushort_t* Bc = Bs + cur * GBUF;
        short8 av[4], bv[4];
#pragma unroll
        for (int i = 0; i < 4; ++i)
            av[i] = *(const short8*)(Ac + (wm + i * 16 + lrow) * 32 + kq);
#pragma unroll
        for (int j = 0; j < 4; ++j)
            bv[j] = *(const short8*)(Bc + (wn + j * 16 + lrow) * 32 + kq);

        if (k + 2 < nsteps) {                // issue tile k+2 into buffer (k+2)%3
            const int nb = (cur + 2 >= 3) ? cur - 1 : cur + 2;
            ushort_t* An = As + nb * GBUF;
            ushort_t* Bn = Bs + nb * GBUF;
            const int ko = (k + 2) * 32;
            g2l16(ga0 + ko, An + flat0);
            g2l16(gb0 + ko, Bn + flat0);
            g2l16(ga1 + ko, An + flat1);
            g2l16(gb1 + ko, Bn + flat1);
        }

#pragma unroll
        for (int i = 0; i < 4; ++i)
#pragma unroll
            for (int j = 0; j < 4; ++j)
                acc[i][j] = __builtin_amdgcn_mfma_f32_16x16x32_bf16(
                    av[i], bv[j], acc[i][j], 0, 0, 0);

        cur = (cur + 1 >= 3) ? 0 : cur + 1;
    }
}

// QKV: z picks weight/dest; writes merged row-major [B*S, D] bf16.
// Q pre-scaled by 0.125*log2(e): attention softmax runs in exp2 domain.
// LDS 3x16KB = 48KB -> 3 blocks/CU = 144KB (fits 160KB).
__global__ __launch_bounds__(256, 3) void gemm_qkv_kernel(
        const ushort_t* __restrict__ A,
        const ushort_t* __restrict__ WqT, const ushort_t* __restrict__ WkT,
        const ushort_t* __restrict__ WvT,
        ushort_t* __restrict__ Qo, ushort_t* __restrict__ Ko,
        ushort_t* __restrict__ Vo) {
    const ushort_t* BT = (blockIdx.z == 0) ? WqT : (blockIdx.z == 1) ? WkT : WvT;
    ushort_t* C        = (blockIdx.z == 0) ? Qo  : (blockIdx.z == 1) ? Ko  : Vo;
    const float sc     = (blockIdx.z == 0) ? 0.18033688f : 1.0f;  // 0.125*log2(e)
    __shared__ __align__(16) ushort_t As[3 * GBUF];
    __shared__ __align__(16) ushort_t Bs[3 * GBUF];
    const int m0 = blockIdx.y * 128, n0 = blockIdx.x * 128;

    floatx4 acc[4][4] = {};
    gemm_tile(A, BT, m0, n0, As, Bs, acc);

    const int tid = threadIdx.x;
    const int w = tid >> 6, wm = (w >> 1) * 64, wn = (w & 1) * 64;
    const int lrow = tid & 15;
    const int rquad = ((tid & 63) >> 4) * 4;
#pragma unroll
    for (int i = 0; i < 4; ++i) {
        const int mbase = m0 + wm + i * 16 + rquad;
#pragma unroll
        for (int j = 0; j < 4; ++j) {
            const int gn = n0 + wn + j * 16 + lrow;
#pragma unroll
            for (int r = 0; r < 4; ++r)
                C[(size_t)(mbase + r) * D_DIM + gn] = f2bf(acc[i][j][r] * sc);
        }
    }
}

// Output projection: f32 out = A @ Wo + bo. (R10 exact form — R11's 128x64
// variant was null-to-negative and is reverted.)
__global__ __launch_bounds__(256, 2) void gemm_out_kernel(
        const ushort_t* __restrict__ A, const ushort_t* __restrict__ WoT,
        const float* __restrict__ bias, float* __restrict__ C) {
    __shared__ __align__(16) ushort_t As[3 * GBUF];
    __shared__ __align__(16) ushort_t Bs[3 * GBUF];
    const int m0 = blockIdx.y * 128, n0 = blockIdx.x * 128;

    floatx4 acc[4][4] = {};
    gemm_tile(A, WoT, m0, n0, As, Bs, acc);

    const int tid = threadIdx.x;
    const int w = tid >> 6, wm = (w >> 1) * 64, wn = (w & 1) * 64;
    const int lrow = tid & 15;
    const int rquad = ((tid & 63) >> 4) * 4;
#pragma unroll
    for (int i = 0; i < 4; ++i) {
        const int mbase = m0 + wm + i * 16 + rquad;
#pragma unroll
        for (int j = 0; j < 4; ++j) {
            const int gn = n0 + wn + j * 16 + lrow;
            const float badd = bias[gn];
#pragma unroll
            for (int r = 0; r < 4; ++r)
                C[(size_t)(mbase + r) * D_DIM + gn] = acc[i][j][r] + badd;
        }
    }
}

// ---------------------------------------------------------------- MFMA flash attention
// R12: T12 swapped-QK in-register softmax. S^T = mfma(K, Q) (operand swap;
// identical fragment layouts make this argument order only). Lane holds 16
// scores for ONE q-row (q=col, keys=16j+4quad+r):
//  - row max: 15 in-reg fmax + 2 shfl (xor16/32), was 16 shfl
//  - P->bf16: 8 v_cvt_pk_bf16_f32 (RTNE == old f2bf, bit-identical)
//  - P->PV A-frag: 16 ds_bpermute + 8 cndmask replaces 16 ds_write_b16
//    + lgkmcnt stall + 8 ds_read_b128  (dest (quad,col,kc,d) pulls
//    pk[2kc+(quad>>1)][d&1] from lane col+16*(d>>1)+32*(quad&1))
//  - rescale al & epilogue l redistributed to q=quad*4+r via 4 bpermutes
//  - Ps LDS deleted (24.5 -> 16.4 KB); mrun/lrun now scalars.
// Staging/prefetch/grid/swizzle byte-identical to R10.
__global__ __launch_bounds__(256, 4) void attn_mfma_kernel(
        const ushort_t* __restrict__ Q, const ushort_t* __restrict__ K,
        const ushort_t* __restrict__ V, ushort_t* __restrict__ O) {
    __shared__ __align__(16) ushort_t Ks[64 * 64];      // [key][d] swizzled
    __shared__ __align__(16) ushort_t Vt[64 * 64];      // [d][key] swizzled

    const int bh  = blockIdx.x;
    const int b   = bh >> 4, h = bh & 15;
    const int g   = blockIdx.y & 7;            // CU-balanced qt map
    const int p   = blockIdx.y >> 3;
    const int qt  = (p == 0) ? g : (p == 1) ? (15 - g)
                  : (p == 2) ? (16 + g) : (31 - g);
    const int q0  = qt * 64;
    const int tid = threadIdx.x;
    const int wq  = tid >> 6;
    const int lane = tid & 63;
    const int col  = lane & 15;
    const int quad = lane >> 4;
    const int c7 = col & 7;
    const int qw0  = q0 + wq * 16;             // wave's first q-row
    const size_t rowbase = (size_t)b * S_LEN;
    const int ch0 = h * HD;
    const int q4 = quad * 4;
    const int gbase = (lane & 48) << 2;        // own quad-group lane base (bytes)

    // K staging: thread = (key, 32B d-chunk)
    const int skey = tid >> 2;           // 0..63
    const int schk = tid & 3;            // 0..3
    // V staging: thread = (key-pair, 8-wide d-chunk)
    const int vkp = tid & 31;            // key-pair 0..31
    const int vdc = tid >> 5;            // d-chunk 0..7

    // Q fragment (B-operand after swap): lane holds Q[qw0+col][kc*32+quad*8+e]
    short8 aq[2];
#pragma unroll
    for (int kc = 0; kc < 2; ++kc)
        aq[kc] = *(const short8*)(Q + (rowbase + qw0 + col) * D_DIM
                                    + ch0 + kc * 32 + quad * 8);

    floatx4 oacc[4] = {};
    float mrun0 = -1e30f, lrun0 = 0.0f;        // state for q-row = qw0+col

    const int ntiles = qt + 1;

    // ---- prologue: load tile 0 into registers
    short8 krA, krB, vrA, vrB;
    {
        const ushort_t* kg = K + (rowbase + skey) * D_DIM + ch0 + schk * 16;
        krA = *(const short8*)(kg);
        krB = *(const short8*)(kg + 8);
        const ushort_t* vg = V + (rowbase + 2 * vkp) * D_DIM + ch0 + vdc * 8;
        vrA = *(const short8*)(vg);
        vrB = *(const short8*)(vg + D_DIM);
    }

    for (int t = 0; t < ntiles; ++t) {
        const int kb = t * 64;
        __syncthreads();   // previous tile's LDS reads complete
        // ---- write staged registers to LDS (K swizzled, V transposed pair-packed)
        {
            const int sw = skey & 7;
            *(short8*)(Ks + skey * 64 + (((2 * schk) ^ sw) << 3)) = krA;
            *(short8*)(Ks + skey * 64 + (((2 * schk + 1) ^ sw) << 3)) = krB;
        }
#pragma unroll
        for (int e = 0; e < 8; ++e) {
            const int d = vdc * 8 + e;
            const uint_t pkv = (uint_t)(ushort_t)vrA[e] | ((uint_t)(ushort_t)vrB[e] << 16);
            *(uint_t*)(Vt + d * 64 + ((2 * vkp) ^ ((d & 7) << 3))) = pkv;
        }
        // ---- prefetch next tile into registers (overlaps with compute below)
        {
            const int kbn = (t + 1 < ntiles) ? (t + 1) * 64 : 0;   // clamp: valid addr
            const ushort_t* kg = K + (rowbase + kbn + skey) * D_DIM + ch0 + schk * 16;
            krA = *(const short8*)(kg);
            krB = *(const short8*)(kg + 8);
            const ushort_t* vg = V + (rowbase + kbn + 2 * vkp) * D_DIM + ch0 + vdc * 8;
            vrA = *(const short8*)(vg);
            vrB = *(const short8*)(vg + D_DIM);
        }
        __syncthreads();   // LDS tile ready

        if (kb <= qw0 + 15) {        // wave-uniform: tile has valid keys
            // ---- S^T = K Q^T: sa[j][r] = S[key=kb+16j+4quad+r][q=qw0+col]
            floatx4 sa[4] = {};
            __builtin_amdgcn_s_setprio(1);
#pragma unroll
            for (int kc = 0; kc < 2; ++kc)
#pragma unroll
                for (int j = 0; j < 4; ++j) {
                    const short8 bk = *(const short8*)(
                        Ks + (j * 16 + col) * 64 + (((kc * 4 + quad) ^ c7) << 3));
                    sa[j] = __builtin_amdgcn_mfma_f32_16x16x32_bf16(
                        bk, aq[kc], sa[j], 0, 0, 0);   // SWAPPED operands
                }
            __builtin_amdgcn_s_setprio(0);

            const bool needmask = (kb + 63 > qw0);
            // ---- causal mask: key = kb+16j+4quad+r vs row = qw0+col
            if (needmask) {
                const int qrow = qw0 + col;
#pragma unroll
                for (int j = 0; j < 4; ++j)
#pragma unroll
                    for (int r = 0; r < 4; ++r)
                        if (kb + j * 16 + q4 + r > qrow) sa[j][r] = -1e30f;
            }
            // ---- softmax for q=col: in-register max over 16 + 2 shfl
            float mx = sa[0][0];
#pragma unroll
            for (int j = 0; j < 4; ++j)
#pragma unroll
                for (int r = 0; r < 4; ++r) mx = fmaxf(mx, sa[j][r]);
            mx = fmaxf(mx, __shfl_xor(mx, 16));
            mx = fmaxf(mx, __shfl_xor(mx, 32));
            const float mn = fmaxf(mrun0, mx);
            const float al = __builtin_amdgcn_exp2f(mrun0 - mn);
            mrun0 = mn;
            float rs = 0.0f;
#pragma unroll
            for (int j = 0; j < 4; ++j)
#pragma unroll
                for (int r = 0; r < 4; ++r) {
                    const float p2 = __builtin_amdgcn_exp2f(sa[j][r] - mn);
                    sa[j][r] = p2;
                    rs += p2;
                }
            lrun0 = lrun0 * al + rs;
            // ---- redistribute al (q=col) -> q=quad*4+r; rescale O
            float al4[4];
#pragma unroll
            for (int r = 0; r < 4; ++r)
                al4[r] = __int_as_float(__builtin_amdgcn_ds_bpermute(
                    gbase + ((q4 + r) << 2), __float_as_int(al)));
#pragma unroll
            for (int jd = 0; jd < 4; ++jd)
#pragma unroll
                for (int r = 0; r < 4; ++r) oacc[jd][r] *= al4[r];
            // ---- pack P (bf16 pairs): pk[j][p] = keys 16j+4quad+2p,+1 for q=col
            uint_t pk[4][2];
#pragma unroll
            for (int j = 0; j < 4; ++j) {
                pk[j][0] = cvtpk_bf16(sa[j][0], sa[j][1]);
                pk[j][1] = cvtpk_bf16(sa[j][2], sa[j][3]);
            }
            // ---- exchange: dest (quad,col) slot (kc,d) = pk[2kc+(quad>>1)][d&1]
            //      from lane col + 16*(d>>1) + 32*(quad&1)
            const int aLo = (col + ((quad & 1) << 5)) << 2;
            const int aHi = aLo + 64;
            uint_t res[4][2][2];
#pragma unroll
            for (int j = 0; j < 4; ++j)
#pragma unroll
                for (int p2 = 0; p2 < 2; ++p2) {
                    res[j][p2][0] = (uint_t)__builtin_amdgcn_ds_bpermute(aLo, (int)pk[j][p2]);
                    res[j][p2][1] = (uint_t)__builtin_amdgcn_ds_bpermute(aHi, (int)pk[j][p2]);
                }
            const bool b5 = (quad >> 1) != 0;
            union { short8 s; uint_t u[4]; } ap[2];
#pragma unroll
            for (int kc = 0; kc < 2; ++kc)
#pragma unroll
                for (int d = 0; d < 4; ++d)
                    ap[kc].u[d] = b5 ? res[2 * kc + 1][d & 1][d >> 1]
                                     : res[2 * kc][d & 1][d >> 1];
            // ---- O += P V
            __builtin_amdgcn_s_setprio(1);
#pragma unroll
            for (int kc = 0; kc < 2; ++kc)
#pragma unroll
                for (int jd = 0; jd < 4; ++jd) {
                    const short8 bv = *(const short8*)(
                        Vt + (jd * 16 + col) * 64 + (((kc * 4 + quad) ^ c7) << 3));
                    oacc[jd] = __builtin_amdgcn_mfma_f32_16x16x32_bf16(
                        ap[kc].s, bv, oacc[jd], 0, 0, 0);
                }
            __builtin_amdgcn_s_setprio(0);
        }
    }

    // ---- epilogue: finish l (q=col) across quads, redistribute to q=quad*4+r
    float l = lrun0;
    l += __shfl_xor(l, 16);
    l += __shfl_xor(l, 32);
#pragma unroll
    for (int r = 0; r < 4; ++r) {
        const float lr = __int_as_float(__builtin_amdgcn_ds_bpermute(
            gbase + ((q4 + r) << 2), __float_as_int(l)));
        const float inv = 1.0f / lr;
        const int row = qw0 + q4 + r;
#pragma unroll
        for (int jd = 0; jd < 4; ++jd)
            O[(rowbase + row) * D_DIM + ch0 + jd * 16 + col] =
                f2bf(oacc[jd][r] * inv);
    }
}

// ---------------------------------------------------------------- launch
extern "C" void kernel_launch(void* const* d_in, const int* in_sizes, int n_in,
                              void* d_out, int out_size, void* d_ws, size_t ws_size,
                              hipStream_t stream) {
    const float* x  = (const float*)d_in[0];
    const float* Wq = (const float*)d_in[1];
    const float* Wk = (const float*)d_in[2];
    const float* Wv = (const float*)d_in[3];
    const float* Wo = (const float*)d_in[4];
    const float* bo = (const float*)d_in[5];
    float* out = (float*)d_out;                // f32 output

    char* ws = (char*)d_ws;
    const size_t MB = 1024 * 1024;
    ushort_t* xb  = (ushort_t*)(ws + 0 * MB);   // 8 MB
    ushort_t* WqT = (ushort_t*)(ws + 8 * MB);   // 2 MB each
    ushort_t* WkT = (ushort_t*)(ws + 10 * MB);
    ushort_t* WvT = (ushort_t*)(ws + 12 * MB);
    ushort_t* WoT = (ushort_t*)(ws + 14 * MB);
    ushort_t* Qb  = (ushort_t*)(ws + 16 * MB);  // [B*S, D] bf16, 8 MB each
    ushort_t* Kb  = (ushort_t*)(ws + 24 * MB);
    ushort_t* Vb  = (ushort_t*)(ws + 32 * MB);
    ushort_t* Ob  = (ushort_t*)(ws + 40 * MB);  // total 48 MB

    cast_x_kernel<<<4096, 256, 0, stream>>>(x, xb);
    transpose4_kernel<<<dim3(16, 16, 4), 256, 0, stream>>>(
        Wq, Wk, Wv, Wo, WqT, WkT, WvT, WoT);

    gemm_qkv_kernel<<<dim3(8, 32, 3), 256, 0, stream>>>(
        xb, WqT, WkT, WvT, Qb, Kb, Vb);

    attn_mfma_kernel<<<dim3(32, 32), 256, 0, stream>>>(Qb, Kb, Vb, Ob);

    gemm_out_kernel<<<dim3(8, 32), 256, 0, stream>>>(Ob, WoT, bo, out);
}